// Round 1
// 549.754 us; speedup vs baseline: 1.0202x; 1.0202x over previous
//
#include <hip/hip_runtime.h>
#include <hip/hip_bf16.h>

typedef __bf16 bf16x8 __attribute__((ext_vector_type(8)));
typedef __bf16 bf16x4 __attribute__((ext_vector_type(4)));
typedef float  floatx4 __attribute__((ext_vector_type(4)));

#define L_SEQ 4096

// ---------------- fp32 -> bf16 cast, 8 elems/thread ----------------
__global__ void cvt_bf16_kernel(const float* __restrict__ src,
                                __bf16* __restrict__ dst, int n8)
{
    int i = blockIdx.x * blockDim.x + threadIdx.x;
    if (i >= n8) return;
    const float4* s = (const float4*)src + (size_t)i * 2;
    float4 f0 = s[0], f1 = s[1];
    bf16x8 o;
    o[0] = (__bf16)f0.x; o[1] = (__bf16)f0.y; o[2] = (__bf16)f0.z; o[3] = (__bf16)f0.w;
    o[4] = (__bf16)f1.x; o[5] = (__bf16)f1.y; o[6] = (__bf16)f1.z; o[7] = (__bf16)f1.w;
    *((bf16x8*)dst + i) = o;
}

// ---------------- 3 weight transposes in one launch: dst[n][k] = (bf16)src[k][n] ----------------
__global__ void transpose_cvt3_kernel(const float* __restrict__ WQ,
                                      const float* __restrict__ WK,
                                      const float* __restrict__ WO,
                                      __bf16* __restrict__ Wqk,
                                      __bf16* __restrict__ Wo)
{
    const int z = blockIdx.z;
    const float* src = (z == 0) ? WQ : (z == 1) ? WK : WO;
    __bf16* dst = (z == 0) ? Wqk : (z == 1) ? (Wqk + (size_t)1024 * 1024) : Wo;

    __shared__ float tile[32][33];
    int tx = threadIdx.x & 31, ty = threadIdx.x >> 5;   // 32 x 8
    int n0 = blockIdx.x * 32, k0 = blockIdx.y * 32;
    #pragma unroll
    for (int i = 0; i < 32; i += 8)
        tile[ty + i][tx] = src[(size_t)(k0 + ty + i) * 1024 + n0 + tx];
    __syncthreads();
    #pragma unroll
    for (int i = 0; i < 32; i += 8)
        dst[(size_t)(n0 + ty + i) * 1024 + k0 + tx] = (__bf16)tile[tx][ty + i];
}

// ---------------- global-token projections, k-split x8 ----------------
__global__ void akv_part_kernel(const float* __restrict__ ax,
                                const float* __restrict__ Wk,
                                const float* __restrict__ Wv,
                                float* __restrict__ part)
{
    int b = blockIdx.x, kv = blockIdx.y, z = blockIdx.z;
    int n = threadIdx.x * 4;
    const float* W   = kv ? Wv : Wk;
    const float* axr = ax + (size_t)b * 1024 + z * 128;
    float4 acc = {0.f, 0.f, 0.f, 0.f};
    for (int k = 0; k < 128; ++k) {
        float a = axr[k];
        float4 w = *(const float4*)(W + (size_t)(z * 128 + k) * 1024 + n);
        acc.x = fmaf(a, w.x, acc.x);
        acc.y = fmaf(a, w.y, acc.y);
        acc.z = fmaf(a, w.z, acc.z);
        acc.w = fmaf(a, w.w, acc.w);
    }
    *(float4*)(part + (((size_t)(b * 2 + kv)) * 8 + z) * 1024 + n) = acc;
}

__global__ void akv_reduce_kernel(const float* __restrict__ part,
                                  const float* __restrict__ bk,
                                  const float* __restrict__ bv,
                                  float* __restrict__ akv)
{
    int b = blockIdx.x, kv = blockIdx.y;
    int n = threadIdx.x * 4;
    float4 acc = *(const float4*)((kv ? bv : bk) + n);
    #pragma unroll
    for (int z = 0; z < 8; ++z) {
        float4 p = *(const float4*)(part + (((size_t)(b * 2 + kv)) * 8 + z) * 1024 + n);
        acc.x += p.x; acc.y += p.y; acc.z += p.z; acc.w += p.w;
    }
    *(float4*)(akv + ((size_t)b * 2 + kv) * 1024 + n) = acc;
}

// =====================================================================================
// 256x256 8-phase bf16 GEMM (T2+T3+T4+T5 stack), C[M][N] = A[M][K] * Bt[N][K]^T + bias
//   BM=BN=256, BK=64, 8 waves (2M x 4N), 512 threads, 128 KiB LDS (1 block/CU).
//   LDS layout per operand per buffer: 16 row-groups x 2 col-groups of 16x32 subtiles
//   (1024 B each), st_16x32 swizzle: phys ^= ((phys>>9)&1)<<5 within each subtile.
//   Staging: global_load_lds width=16, LINEAR LDS dest (1 subtile per wave-chunk),
//   inverse swizzle applied to the per-lane GLOBAL source address (rule 21).
//   Phase schedule per K-tile t (buf p = t&1), compute halves match wave ownership:
//     A-h0 = rows [0,64)+[128,192)   (mi 0-3 of both wave-groups), A-h1 = the rest
//     B-h0 = cols [wn,wn+32) stripes (ni 0-1), B-h1 = ni 2-3 stripes
//     ph1: read A-h0,B-h0 (12 ds_read_b128) | stage (t+1).A-h1 -> buf p^1 | MFMA q(0,0)
//     ph2: read B-h1 (4)                    | stage (t+2).A-h0 -> buf p   | MFMA q(0,1)
//     ph3: read A-h1 (8)                    | stage (t+2).B-h0 -> buf p   | MFMA q(1,1)
//     ph4: (regs only)                      | stage (t+2).B-h1 -> buf p; vmcnt(6) | q(1,0)
//   vmcnt(6) leaves the 3 newest half-tiles in flight -> tile t+1 fully staged.
//   Each stage only overwrites a region whose ds_reads finished >=1 barrier earlier.
// =====================================================================================
#define GLDS(gp, lp) __builtin_amdgcn_global_load_lds(                              \
    (const __attribute__((address_space(1))) void*)(gp),                            \
    (__attribute__((address_space(3))) void*)(lp), 16, 0, 0)

#define STAGE_A(hi, kt, buf) do {                                                   \
    GLDS(A + aS[0][hi] + (size_t)(kt) * 64, smem + (buf) * 65536 + aD[0][hi]);      \
    GLDS(A + aS[1][hi] + (size_t)(kt) * 64, smem + (buf) * 65536 + aD[1][hi]);      \
} while (0)
#define STAGE_B(hi, kt, buf) do {                                                   \
    GLDS(Bt + bS[0][hi] + (size_t)(kt) * 64, smem + (buf) * 65536 + bD[0][hi]);     \
    GLDS(Bt + bS[1][hi] + (size_t)(kt) * 64, smem + (buf) * 65536 + bD[1][hi]);     \
} while (0)

#define RDA(cb, mi, kk) (*(const bf16x8*)(smem + (cb) + awoff + ((mi) << 11) + ((kk) << 10)))
#define RDB(cb, ni, kk) (*(const bf16x8*)(smem + (cb) + bwoff + ((ni) << 11) + ((kk) << 10)))
#define MFMA16(af, bfv, c) (c) = __builtin_amdgcn_mfma_f32_16x16x32_bf16((af), (bfv), (c), 0, 0, 0)

template <int NT, bool OUT_F32>
__global__ __launch_bounds__(512, 2) void gemm256_kernel(
    const __bf16* __restrict__ A, const __bf16* __restrict__ Bt,
    const float* __restrict__ b0, const float* __restrict__ b1, int nsplit,
    void* __restrict__ Cp, int M, int N, int K)
{
    __shared__ __align__(16) char smem[131072];   // [buf:2][A|B][32 subtiles][1024B]

    const int bid = blockIdx.x;
    const int xcd = bid & 7, g = bid >> 3;        // XCD-aware: nwg % 8 == 0 (bijective)
    int mt, nt;
    if constexpr (NT == 8) { nt = xcd;     mt = g; }                       // 1 N-col per XCD
    else                   { nt = xcd & 3; mt = (xcd >> 2) * ((M >> 8) >> 1) + g; } // 2 XCDs/N-col
    const int m0 = mt << 8, n0 = nt << 8;

    const int tid  = threadIdx.x;
    const int wave = tid >> 6, lane = tid & 63;
    const int l15  = lane & 15, quad = lane >> 4;
    const int ntile = K >> 6;

    // ---- staging addresses: chunk = (wave, c); rg_local = wave, cg = c ----
    // A half hi covers row-groups {0..3,8..11}+4*hi ; B half hi covers {0,1,4,5,...}+2*hi
    const int rowin = lane >> 2;                                   // row within subtile
    const int colel = ((lane & 3) << 3) ^ (((lane >> 5) & 1) << 4); // inverse-swizzled col (elems)
    size_t aS[2][2], bS[2][2];
    int    aD[2][2], bD[2][2];
    #pragma unroll
    for (int hi = 0; hi < 2; ++hi) {
        const int rgA = (wave & 3) + ((wave >> 2) << 3) + hi * 4;
        const int rgB = ((wave >> 1) << 2) + (wave & 1) + hi * 2;
        #pragma unroll
        for (int c = 0; c < 2; ++c) {
            aS[c][hi] = (size_t)(m0 + rgA * 16 + rowin) * K + c * 32 + colel;
            aD[c][hi] = (rgA * 2 + c) << 10;
            bS[c][hi] = (size_t)(n0 + rgB * 16 + rowin) * K + c * 32 + colel;
            bD[c][hi] = 32768 + ((rgB * 2 + c) << 10);
        }
    }

    // ---- fragment ds_read offsets (swizzled): subtile(r>>4, kk)*1024 + (r&15)*64
    //      + (quad*16 ^ ((r>>3)&1)<<5); (r>>3)&1 == (l15>>3)&1 for all frags ----
    const int alane = (l15 << 6) + ((quad << 4) ^ (((l15 >> 3) & 1) << 5));
    const int awoff = (((wave >> 2) * 8) << 11) + alane;            // + mi<<11 + kk<<10
    const int bwoff = 32768 + (((wave & 3) * 4) << 11) + alane;     // + ni<<11 + kk<<10

    floatx4 acc[8][4] = {};

    // ---- prologue: tile0 (4 halves) + tile1 h0..h2 (3 halves); keep 3 in flight ----
    STAGE_A(0, 0, 0); STAGE_A(1, 0, 0); STAGE_B(0, 0, 0); STAGE_B(1, 0, 0);
    STAGE_A(0, 1, 1); STAGE_B(0, 1, 1); STAGE_B(1, 1, 1);
    asm volatile("s_waitcnt vmcnt(6)" ::: "memory");   // tile0's 8 loads retired
    __builtin_amdgcn_s_barrier();

    for (int t = 0; t < ntile; ++t) {
        const int p  = t & 1;
        const int cb = p * 65536;
        bf16x8 a0[4][2], a1[4][2], b0f[2][2], b1f[2][2];

        // ---------- phase 1 ----------
        #pragma unroll
        for (int mi = 0; mi < 4; ++mi) { a0[mi][0] = RDA(cb, mi, 0); a0[mi][1] = RDA(cb, mi, 1); }
        #pragma unroll
        for (int ni = 0; ni < 2; ++ni) { b0f[ni][0] = RDB(cb, ni, 0); b0f[ni][1] = RDB(cb, ni, 1); }
        if (t + 1 < ntile) STAGE_A(1, t + 1, p ^ 1);
        __builtin_amdgcn_s_barrier();
        asm volatile("s_waitcnt lgkmcnt(0)" ::: "memory");
        __builtin_amdgcn_s_setprio(1);
        #pragma unroll
        for (int mi = 0; mi < 4; ++mi)
            #pragma unroll
            for (int ni = 0; ni < 2; ++ni) {
                MFMA16(a0[mi][0], b0f[ni][0], acc[mi][ni]);
                MFMA16(a0[mi][1], b0f[ni][1], acc[mi][ni]);
            }
        __builtin_amdgcn_s_setprio(0);
        __builtin_amdgcn_s_barrier();

        // ---------- phase 2 ----------
        #pragma unroll
        for (int ni = 0; ni < 2; ++ni) { b1f[ni][0] = RDB(cb, ni + 2, 0); b1f[ni][1] = RDB(cb, ni + 2, 1); }
        if (t + 2 < ntile) STAGE_A(0, t + 2, p);
        __builtin_amdgcn_s_barrier();
        asm volatile("s_waitcnt lgkmcnt(0)" ::: "memory");
        __builtin_amdgcn_s_setprio(1);
        #pragma unroll
        for (int mi = 0; mi < 4; ++mi)
            #pragma unroll
            for (int ni = 0; ni < 2; ++ni) {
                MFMA16(a0[mi][0], b1f[ni][0], acc[mi][ni + 2]);
                MFMA16(a0[mi][1], b1f[ni][1], acc[mi][ni + 2]);
            }
        __builtin_amdgcn_s_setprio(0);
        __builtin_amdgcn_s_barrier();

        // ---------- phase 3 ----------
        #pragma unroll
        for (int mi = 0; mi < 4; ++mi) { a1[mi][0] = RDA(cb, mi + 4, 0); a1[mi][1] = RDA(cb, mi + 4, 1); }
        if (t + 2 < ntile) STAGE_B(0, t + 2, p);
        __builtin_amdgcn_s_barrier();
        asm volatile("s_waitcnt lgkmcnt(0)" ::: "memory");
        __builtin_amdgcn_s_setprio(1);
        #pragma unroll
        for (int mi = 0; mi < 4; ++mi)
            #pragma unroll
            for (int ni = 0; ni < 2; ++ni) {
                MFMA16(a1[mi][0], b1f[ni][0], acc[mi + 4][ni + 2]);
                MFMA16(a1[mi][1], b1f[ni][1], acc[mi + 4][ni + 2]);
            }
        __builtin_amdgcn_s_setprio(0);
        __builtin_amdgcn_s_barrier();

        // ---------- phase 4 (regs only; counted vmcnt once per K-tile) ----------
        if (t + 2 < ntile) {
            STAGE_B(1, t + 2, p);
            asm volatile("s_waitcnt vmcnt(6)" ::: "memory");  // (t+1) fully staged
        } else {
            asm volatile("s_waitcnt vmcnt(0)" ::: "memory");  // epilogue drain
        }
        __builtin_amdgcn_s_barrier();
        __builtin_amdgcn_s_setprio(1);
        #pragma unroll
        for (int mi = 0; mi < 4; ++mi)
            #pragma unroll
            for (int ni = 0; ni < 2; ++ni) {
                MFMA16(a1[mi][0], b0f[ni][0], acc[mi + 4][ni]);
                MFMA16(a1[mi][1], b0f[ni][1], acc[mi + 4][ni]);
            }
        __builtin_amdgcn_s_setprio(0);
        __builtin_amdgcn_s_barrier();
    }

    // ---- epilogue: C/D layout col = lane&15, row = quad*4 + r (m89/m91-verified) ----
    const int gmw = m0 + (wave >> 2) * 128;
    const int gnw = n0 + (wave & 3) * 64;
    #pragma unroll
    for (int ni = 0; ni < 4; ++ni) {
        int gn = gnw + ni * 16 + l15;
        float bv = (gn < nsplit) ? b0[gn] : b1[gn - nsplit];
        #pragma unroll
        for (int mi = 0; mi < 8; ++mi) {
            int gm = gmw + mi * 16 + quad * 4;
            #pragma unroll
            for (int r = 0; r < 4; ++r) {
                float v = acc[mi][ni][r] + bv;
                if constexpr (OUT_F32)
                    ((float*)Cp)[(size_t)(gm + r) * N + gn] = v;
                else
                    ((__bf16*)Cp)[(size_t)(gm + r) * N + gn] = (__bf16)v;
            }
        }
    }
}

// ---------------- attention: 8 tokens per block ----------------
__global__ void attn_kernel(const __bf16* __restrict__ qk,
                            const float* __restrict__ akv,
                            __bf16* __restrict__ att)
{
    const int t  = threadIdx.x;        // head = t>>4, 4 dims each
    const int c4 = t * 4;
    const int m0 = blockIdx.x * 8;     // 8 consecutive tokens, same batch (8 | 4096)
    const int l0 = m0 & (L_SEQ - 1);
    const int b  = m0 >> 12;

    float kr[10][4];
    #pragma unroll
    for (int j = 0; j < 10; ++j) {
        int ll = l0 - 1 + j;
        if (ll >= 0 && ll < L_SEQ) {
            bf16x4 kv = *(const bf16x4*)(qk + (size_t)(m0 - 1 + j) * 2048 + 1024 + c4);
            kr[j][0] = kv[0]; kr[j][1] = kv[1]; kr[j][2] = kv[2]; kr[j][3] = kv[3];
        } else {
            kr[j][0] = kr[j][1] = kr[j][2] = kr[j][3] = 0.f;
        }
    }
    float4 ak4 = *(const float4*)(akv + ((size_t)b * 2 + 0) * 1024 + c4);
    float4 av4 = *(const float4*)(akv + ((size_t)b * 2 + 1) * 1024 + c4);

    #pragma unroll
    for (int i = 0; i < 8; ++i) {
        const int m = m0 + i;
        bf16x4 qv = *(const bf16x4*)(qk + (size_t)m * 2048 + c4);
        float q0 = qv[0], q1 = qv[1], q2 = qv[2], q3 = qv[3];

        float p0 = q0 * ak4.x + q1 * ak4.y + q2 * ak4.z + q3 * ak4.w;
        float p1 = q0 * kr[i][0]     + q1 * kr[i][1]     + q2 * kr[i][2]     + q3 * kr[i][3];
        float p2 = q0 * kr[i + 1][0] + q1 * kr[i + 1][1] + q2 * kr[i + 1][2] + q3 * kr[i + 1][3];
        float p3 = q0 * kr[i + 2][0] + q1 * kr[i + 2][1] + q2 * kr[i + 2][2] + q3 * kr[i + 2][3];
        #pragma unroll
        for (int off = 1; off < 16; off <<= 1) {
            p0 += __shfl_xor(p0, off, 64);
            p1 += __shfl_xor(p1, off, 64);
            p2 += __shfl_xor(p2, off, 64);
            p3 += __shfl_xor(p3, off, 64);
        }
        const float sc = 0.125f;   // 1/sqrt(64)
        float s0 = p0 * sc, s1 = p1 * sc, s2 = p2 * sc, s3 = p3 * sc;
        float mx = fmaxf(fmaxf(s0, s1), fmaxf(s2, s3));
        float e0 = __expf(s0 - mx), e1 = __expf(s1 - mx), e2 = __expf(s2 - mx), e3 = __expf(s3 - mx);
        float inv = 1.f / (e0 + e1 + e2 + e3);

        bf16x4 o;
        o[0] = (__bf16)((e0 * av4.x + e1 * kr[i][0] + e2 * kr[i + 1][0] + e3 * kr[i + 2][0]) * inv);
        o[1] = (__bf16)((e0 * av4.y + e1 * kr[i][1] + e2 * kr[i + 1][1] + e3 * kr[i + 2][1]) * inv);
        o[2] = (__bf16)((e0 * av4.z + e1 * kr[i][2] + e2 * kr[i + 1][2] + e3 * kr[i + 2][2]) * inv);
        o[3] = (__bf16)((e0 * av4.w + e1 * kr[i][3] + e2 * kr[i + 1][3] + e3 * kr[i + 2][3]) * inv);
        *(bf16x4*)(att + (size_t)m * 1024 + c4) = o;
    }
}

extern "C" void kernel_launch(void* const* d_in, const int* in_sizes, int n_in,
                              void* d_out, int out_size, void* d_ws, size_t ws_size,
                              hipStream_t stream)
{
    const float* x    = (const float*)d_in[0];
    const float* ax   = (const float*)d_in[1];
    const float* WQ_w = (const float*)d_in[2];
    const float* WQ_b = (const float*)d_in[3];
    const float* WK_w = (const float*)d_in[4];
    const float* WK_b = (const float*)d_in[5];
    const float* WV_w = (const float*)d_in[6];
    const float* WV_b = (const float*)d_in[7];
    const float* WO_w = (const float*)d_in[8];
    const float* WO_b = (const float*)d_in[9];
    float* out = (float*)d_out;

    const int M = 8 * 4096;          // 32768 tokens

    // workspace layout
    char* ws = (char*)d_ws;
    __bf16* xb   = (__bf16*)(ws);                       //  67,108,864 B
    __bf16* Wqk  = (__bf16*)(ws + 67108864);            //   4,194,304 B  (2048 x 1024, N-major)
    __bf16* Wo   = (__bf16*)(ws + 71303168);            //   2,097,152 B  (1024 x 1024, N-major)
    __bf16* qk   = (__bf16*)(ws + 73400320);            // 134,217,728 B  (M x 2048)
    __bf16* att  = (__bf16*)(ws + 207618048);           //  67,108,864 B  (M x 1024)
    float*  akv  = (float*)(ws + 274726912);            //      65,536 B
    float*  akvp = (float*)(ws + 274792448);            //     524,288 B  (partials)

    // 1) x -> bf16
    {
        int n8 = (M * 1024) / 8;   // 4,194,304
        cvt_bf16_kernel<<<n8 / 256, 256, 0, stream>>>(x, xb, n8);
    }
    // 2) weight transpose+cast (one launch)
    transpose_cvt3_kernel<<<dim3(32, 32, 3), 256, 0, stream>>>(WQ_w, WK_w, WO_w, Wqk, Wo);
    // 3) global token projections (fp32), k-split + reduce
    akv_part_kernel<<<dim3(8, 2, 8), 256, 0, stream>>>(ax, WK_w, WV_w, akvp);
    akv_reduce_kernel<<<dim3(8, 2), 256, 0, stream>>>(akvp, WK_b, WV_b, akv);
    // 4) fused Q|K projection GEMM: (M x 2048) = xb @ [WQ|WK]; 256^2 8-phase, NT=8
    gemm256_kernel<8, false><<<(M / 256) * 8, 512, 0, stream>>>(
        xb, Wqk, WQ_b, WK_b, 1024, (void*)qk, M, 2048, 1024);
    // 5) attention -> att (bf16), 8 tokens/block
    attn_kernel<<<M / 8, 256, 0, stream>>>(qk, akv, att);
    // 6) output projection: out (M x 1024 fp32) = att @ WO + WO_b; NT=4
    gemm256_kernel<4, true><<<(M / 256) * 4, 512, 0, stream>>>(
        att, Wo, WO_b, WO_b, 1024, (void*)out, M, 1024, 1024);
}

// Round 2
// 546.955 us; speedup vs baseline: 1.0254x; 1.0051x over previous
//
#include <hip/hip_runtime.h>
#include <hip/hip_bf16.h>

typedef __bf16 bf16x8 __attribute__((ext_vector_type(8)));
typedef __bf16 bf16x4 __attribute__((ext_vector_type(4)));
typedef float  floatx4 __attribute__((ext_vector_type(4)));

#define L_SEQ 4096

// ---------------- fp32 -> bf16 cast, 8 elems/thread ----------------
__global__ void cvt_bf16_kernel(const float* __restrict__ src,
                                __bf16* __restrict__ dst, int n8)
{
    int i = blockIdx.x * blockDim.x + threadIdx.x;
    if (i >= n8) return;
    const float4* s = (const float4*)src + (size_t)i * 2;
    float4 f0 = s[0], f1 = s[1];
    bf16x8 o;
    o[0] = (__bf16)f0.x; o[1] = (__bf16)f0.y; o[2] = (__bf16)f0.z; o[3] = (__bf16)f0.w;
    o[4] = (__bf16)f1.x; o[5] = (__bf16)f1.y; o[6] = (__bf16)f1.z; o[7] = (__bf16)f1.w;
    *((bf16x8*)dst + i) = o;
}

// ---------------- 3 weight transposes in one launch: dst[n][k] = (bf16)src[k][n] ----------------
__global__ void transpose_cvt3_kernel(const float* __restrict__ WQ,
                                      const float* __restrict__ WK,
                                      const float* __restrict__ WO,
                                      __bf16* __restrict__ Wqk,
                                      __bf16* __restrict__ Wo)
{
    const int z = blockIdx.z;
    const float* src = (z == 0) ? WQ : (z == 1) ? WK : WO;
    __bf16* dst = (z == 0) ? Wqk : (z == 1) ? (Wqk + (size_t)1024 * 1024) : Wo;

    __shared__ float tile[32][33];
    int tx = threadIdx.x & 31, ty = threadIdx.x >> 5;   // 32 x 8
    int n0 = blockIdx.x * 32, k0 = blockIdx.y * 32;
    #pragma unroll
    for (int i = 0; i < 32; i += 8)
        tile[ty + i][tx] = src[(size_t)(k0 + ty + i) * 1024 + n0 + tx];
    __syncthreads();
    #pragma unroll
    for (int i = 0; i < 32; i += 8)
        dst[(size_t)(n0 + ty + i) * 1024 + k0 + tx] = (__bf16)tile[tx][ty + i];
}

// ---------------- global-token projections, k-split x8 ----------------
__global__ void akv_part_kernel(const float* __restrict__ ax,
                                const float* __restrict__ Wk,
                                const float* __restrict__ Wv,
                                float* __restrict__ part)
{
    int b = blockIdx.x, kv = blockIdx.y, z = blockIdx.z;
    int n = threadIdx.x * 4;
    const float* W   = kv ? Wv : Wk;
    const float* axr = ax + (size_t)b * 1024 + z * 128;
    float4 acc = {0.f, 0.f, 0.f, 0.f};
    for (int k = 0; k < 128; ++k) {
        float a = axr[k];
        float4 w = *(const float4*)(W + (size_t)(z * 128 + k) * 1024 + n);
        acc.x = fmaf(a, w.x, acc.x);
        acc.y = fmaf(a, w.y, acc.y);
        acc.z = fmaf(a, w.z, acc.z);
        acc.w = fmaf(a, w.w, acc.w);
    }
    *(float4*)(part + (((size_t)(b * 2 + kv)) * 8 + z) * 1024 + n) = acc;
}

__global__ void akv_reduce_kernel(const float* __restrict__ part,
                                  const float* __restrict__ bk,
                                  const float* __restrict__ bv,
                                  float* __restrict__ akv)
{
    int b = blockIdx.x, kv = blockIdx.y;
    int n = threadIdx.x * 4;
    float4 acc = *(const float4*)((kv ? bv : bk) + n);
    #pragma unroll
    for (int z = 0; z < 8; ++z) {
        float4 p = *(const float4*)(part + (((size_t)(b * 2 + kv)) * 8 + z) * 1024 + n);
        acc.x += p.x; acc.y += p.y; acc.z += p.z; acc.w += p.w;
    }
    *(float4*)(akv + ((size_t)b * 2 + kv) * 1024 + n) = acc;
}

// =====================================================================================
// 256x256 8-phase bf16 GEMM (T2+T3+T4+T5), C[M][N] = A[M][K] * Bt[N][K]^T + bias
//   Identical schedule/LDS layout to R1 (refcheck'd). ONLY change: block->tile mapping.
//   L2-locality mapping: each XCD's 32 co-resident blocks form an 8(mt) x 4(nt) subgrid
//   so A-panels are shared by 4 co-resident blocks (L2 hits) and each XCD keeps a fixed
//   2 MB set of B-panels resident.
//     NT==8 (N=2048): nt = (xcd&1)*4 + (s&3); mt = r*32 + (xcd>>1)*8 + (s>>2)
//                     -> each A-panel touched by exactly 2 XCDs (A L2-fill 512->128 MB)
//     NT==4 (N=1024): nt = s&3;              mt = xcd*16 + r*8 + (s>>2)
//                     -> each A-panel touched by exactly 1 XCD (A L2-fill = footprint)
//   (s = g&31 indexes the co-resident round; r = g>>5 the sequential round.)
// =====================================================================================
#define GLDS(gp, lp) __builtin_amdgcn_global_load_lds(                              \
    (const __attribute__((address_space(1))) void*)(gp),                            \
    (__attribute__((address_space(3))) void*)(lp), 16, 0, 0)

#define STAGE_A(hi, kt, buf) do {                                                   \
    GLDS(A + aS[0][hi] + (size_t)(kt) * 64, smem + (buf) * 65536 + aD[0][hi]);      \
    GLDS(A + aS[1][hi] + (size_t)(kt) * 64, smem + (buf) * 65536 + aD[1][hi]);      \
} while (0)
#define STAGE_B(hi, kt, buf) do {                                                   \
    GLDS(Bt + bS[0][hi] + (size_t)(kt) * 64, smem + (buf) * 65536 + bD[0][hi]);     \
    GLDS(Bt + bS[1][hi] + (size_t)(kt) * 64, smem + (buf) * 65536 + bD[1][hi]);     \
} while (0)

#define RDA(cb, mi, kk) (*(const bf16x8*)(smem + (cb) + awoff + ((mi) << 11) + ((kk) << 10)))
#define RDB(cb, ni, kk) (*(const bf16x8*)(smem + (cb) + bwoff + ((ni) << 11) + ((kk) << 10)))
#define MFMA16(af, bfv, c) (c) = __builtin_amdgcn_mfma_f32_16x16x32_bf16((af), (bfv), (c), 0, 0, 0)

template <int NT, bool OUT_F32>
__global__ __launch_bounds__(512, 2) void gemm256_kernel(
    const __bf16* __restrict__ A, const __bf16* __restrict__ Bt,
    const float* __restrict__ b0, const float* __restrict__ b1, int nsplit,
    void* __restrict__ Cp, int M, int N, int K)
{
    __shared__ __align__(16) char smem[131072];   // [buf:2][A|B][32 subtiles][1024B]

    const int bid = blockIdx.x;
    const int xcd = bid & 7, g = bid >> 3;
    const int s = g & 31, r = g >> 5;             // s: co-resident slot, r: round
    int mt, nt;
    if constexpr (NT == 8) {
        nt = ((xcd & 1) << 2) | (s & 3);
        mt = (r << 5) + ((xcd >> 1) << 3) + (s >> 2);
    } else {
        nt = s & 3;
        mt = (xcd << 4) + (r << 3) + (s >> 2);
    }
    const int m0 = mt << 8, n0 = nt << 8;

    const int tid  = threadIdx.x;
    const int wave = tid >> 6, lane = tid & 63;
    const int l15  = lane & 15, quad = lane >> 4;
    const int ntile = K >> 6;

    // ---- staging addresses: chunk = (wave, c); rg_local = wave, cg = c ----
    const int rowin = lane >> 2;                                   // row within subtile
    const int colel = ((lane & 3) << 3) ^ (((lane >> 5) & 1) << 4); // inverse-swizzled col (elems)
    size_t aS[2][2], bS[2][2];
    int    aD[2][2], bD[2][2];
    #pragma unroll
    for (int hi = 0; hi < 2; ++hi) {
        const int rgA = (wave & 3) + ((wave >> 2) << 3) + hi * 4;
        const int rgB = ((wave >> 1) << 2) + (wave & 1) + hi * 2;
        #pragma unroll
        for (int c = 0; c < 2; ++c) {
            aS[c][hi] = (size_t)(m0 + rgA * 16 + rowin) * K + c * 32 + colel;
            aD[c][hi] = (rgA * 2 + c) << 10;
            bS[c][hi] = (size_t)(n0 + rgB * 16 + rowin) * K + c * 32 + colel;
            bD[c][hi] = 32768 + ((rgB * 2 + c) << 10);
        }
    }

    // ---- fragment ds_read offsets (swizzled) ----
    const int alane = (l15 << 6) + ((quad << 4) ^ (((l15 >> 3) & 1) << 5));
    const int awoff = (((wave >> 2) * 8) << 11) + alane;            // + mi<<11 + kk<<10
    const int bwoff = 32768 + (((wave & 3) * 4) << 11) + alane;     // + ni<<11 + kk<<10

    floatx4 acc[8][4] = {};

    // ---- prologue: tile0 (4 halves) + tile1 h0..h2 (3 halves); keep 3 in flight ----
    STAGE_A(0, 0, 0); STAGE_A(1, 0, 0); STAGE_B(0, 0, 0); STAGE_B(1, 0, 0);
    STAGE_A(0, 1, 1); STAGE_B(0, 1, 1); STAGE_B(1, 1, 1);
    asm volatile("s_waitcnt vmcnt(6)" ::: "memory");   // tile0's 8 loads retired
    __builtin_amdgcn_s_barrier();

    for (int t = 0; t < ntile; ++t) {
        const int p  = t & 1;
        const int cb = p * 65536;
        bf16x8 a0[4][2], a1[4][2], b0f[2][2], b1f[2][2];

        // ---------- phase 1 ----------
        #pragma unroll
        for (int mi = 0; mi < 4; ++mi) { a0[mi][0] = RDA(cb, mi, 0); a0[mi][1] = RDA(cb, mi, 1); }
        #pragma unroll
        for (int ni = 0; ni < 2; ++ni) { b0f[ni][0] = RDB(cb, ni, 0); b0f[ni][1] = RDB(cb, ni, 1); }
        if (t + 1 < ntile) STAGE_A(1, t + 1, p ^ 1);
        __builtin_amdgcn_s_barrier();
        asm volatile("s_waitcnt lgkmcnt(0)" ::: "memory");
        __builtin_amdgcn_s_setprio(1);
        #pragma unroll
        for (int mi = 0; mi < 4; ++mi)
            #pragma unroll
            for (int ni = 0; ni < 2; ++ni) {
                MFMA16(a0[mi][0], b0f[ni][0], acc[mi][ni]);
                MFMA16(a0[mi][1], b0f[ni][1], acc[mi][ni]);
            }
        __builtin_amdgcn_s_setprio(0);
        __builtin_amdgcn_s_barrier();

        // ---------- phase 2 ----------
        #pragma unroll
        for (int ni = 0; ni < 2; ++ni) { b1f[ni][0] = RDB(cb, ni + 2, 0); b1f[ni][1] = RDB(cb, ni + 2, 1); }
        if (t + 2 < ntile) STAGE_A(0, t + 2, p);
        __builtin_amdgcn_s_barrier();
        asm volatile("s_waitcnt lgkmcnt(0)" ::: "memory");
        __builtin_amdgcn_s_setprio(1);
        #pragma unroll
        for (int mi = 0; mi < 4; ++mi)
            #pragma unroll
            for (int ni = 0; ni < 2; ++ni) {
                MFMA16(a0[mi][0], b1f[ni][0], acc[mi][ni + 2]);
                MFMA16(a0[mi][1], b1f[ni][1], acc[mi][ni + 2]);
            }
        __builtin_amdgcn_s_setprio(0);
        __builtin_amdgcn_s_barrier();

        // ---------- phase 3 ----------
        #pragma unroll
        for (int mi = 0; mi < 4; ++mi) { a1[mi][0] = RDA(cb, mi + 4, 0); a1[mi][1] = RDA(cb, mi + 4, 1); }
        if (t + 2 < ntile) STAGE_B(0, t + 2, p);
        __builtin_amdgcn_s_barrier();
        asm volatile("s_waitcnt lgkmcnt(0)" ::: "memory");
        __builtin_amdgcn_s_setprio(1);
        #pragma unroll
        for (int mi = 0; mi < 4; ++mi)
            #pragma unroll
            for (int ni = 0; ni < 2; ++ni) {
                MFMA16(a1[mi][0], b1f[ni][0], acc[mi + 4][ni + 2]);
                MFMA16(a1[mi][1], b1f[ni][1], acc[mi + 4][ni + 2]);
            }
        __builtin_amdgcn_s_setprio(0);
        __builtin_amdgcn_s_barrier();

        // ---------- phase 4 (regs only; counted vmcnt once per K-tile) ----------
        if (t + 2 < ntile) {
            STAGE_B(1, t + 2, p);
            asm volatile("s_waitcnt vmcnt(6)" ::: "memory");  // (t+1) fully staged
        } else {
            asm volatile("s_waitcnt vmcnt(0)" ::: "memory");  // epilogue drain
        }
        __builtin_amdgcn_s_barrier();
        __builtin_amdgcn_s_setprio(1);
        #pragma unroll
        for (int mi = 0; mi < 4; ++mi)
            #pragma unroll
            for (int ni = 0; ni < 2; ++ni) {
                MFMA16(a1[mi][0], b0f[ni][0], acc[mi + 4][ni]);
                MFMA16(a1[mi][1], b0f[ni][1], acc[mi + 4][ni]);
            }
        __builtin_amdgcn_s_setprio(0);
        __builtin_amdgcn_s_barrier();
    }

    // ---- epilogue: C/D layout col = lane&15, row = quad*4 + r (m89/m91-verified) ----
    const int gmw = m0 + (wave >> 2) * 128;
    const int gnw = n0 + (wave & 3) * 64;
    #pragma unroll
    for (int ni = 0; ni < 4; ++ni) {
        int gn = gnw + ni * 16 + l15;
        float bv = (gn < nsplit) ? b0[gn] : b1[gn - nsplit];
        #pragma unroll
        for (int mi = 0; mi < 8; ++mi) {
            int gm = gmw + mi * 16 + quad * 4;
            #pragma unroll
            for (int r = 0; r < 4; ++r) {
                float v = acc[mi][ni][r] + bv;
                if constexpr (OUT_F32)
                    ((float*)Cp)[(size_t)(gm + r) * N + gn] = v;
                else
                    ((__bf16*)Cp)[(size_t)(gm + r) * N + gn] = (__bf16)v;
            }
        }
    }
}

// ---------------- attention: 8 tokens per block ----------------
__global__ void attn_kernel(const __bf16* __restrict__ qk,
                            const float* __restrict__ akv,
                            __bf16* __restrict__ att)
{
    const int t  = threadIdx.x;        // head = t>>4, 4 dims each
    const int c4 = t * 4;
    const int m0 = blockIdx.x * 8;     // 8 consecutive tokens, same batch (8 | 4096)
    const int l0 = m0 & (L_SEQ - 1);
    const int b  = m0 >> 12;

    float kr[10][4];
    #pragma unroll
    for (int j = 0; j < 10; ++j) {
        int ll = l0 - 1 + j;
        if (ll >= 0 && ll < L_SEQ) {
            bf16x4 kv = *(const bf16x4*)(qk + (size_t)(m0 - 1 + j) * 2048 + 1024 + c4);
            kr[j][0] = kv[0]; kr[j][1] = kv[1]; kr[j][2] = kv[2]; kr[j][3] = kv[3];
        } else {
            kr[j][0] = kr[j][1] = kr[j][2] = kr[j][3] = 0.f;
        }
    }
    float4 ak4 = *(const float4*)(akv + ((size_t)b * 2 + 0) * 1024 + c4);
    float4 av4 = *(const float4*)(akv + ((size_t)b * 2 + 1) * 1024 + c4);

    #pragma unroll
    for (int i = 0; i < 8; ++i) {
        const int m = m0 + i;
        bf16x4 qv = *(const bf16x4*)(qk + (size_t)m * 2048 + c4);
        float q0 = qv[0], q1 = qv[1], q2 = qv[2], q3 = qv[3];

        float p0 = q0 * ak4.x + q1 * ak4.y + q2 * ak4.z + q3 * ak4.w;
        float p1 = q0 * kr[i][0]     + q1 * kr[i][1]     + q2 * kr[i][2]     + q3 * kr[i][3];
        float p2 = q0 * kr[i + 1][0] + q1 * kr[i + 1][1] + q2 * kr[i + 1][2] + q3 * kr[i + 1][3];
        float p3 = q0 * kr[i + 2][0] + q1 * kr[i + 2][1] + q2 * kr[i + 2][2] + q3 * kr[i + 2][3];
        #pragma unroll
        for (int off = 1; off < 16; off <<= 1) {
            p0 += __shfl_xor(p0, off, 64);
            p1 += __shfl_xor(p1, off, 64);
            p2 += __shfl_xor(p2, off, 64);
            p3 += __shfl_xor(p3, off, 64);
        }
        const float sc = 0.125f;   // 1/sqrt(64)
        float s0 = p0 * sc, s1 = p1 * sc, s2 = p2 * sc, s3 = p3 * sc;
        float mx = fmaxf(fmaxf(s0, s1), fmaxf(s2, s3));
        float e0 = __expf(s0 - mx), e1 = __expf(s1 - mx), e2 = __expf(s2 - mx), e3 = __expf(s3 - mx);
        float inv = 1.f / (e0 + e1 + e2 + e3);

        bf16x4 o;
        o[0] = (__bf16)((e0 * av4.x + e1 * kr[i][0] + e2 * kr[i + 1][0] + e3 * kr[i + 2][0]) * inv);
        o[1] = (__bf16)((e0 * av4.y + e1 * kr[i][1] + e2 * kr[i + 1][1] + e3 * kr[i + 2][1]) * inv);
        o[2] = (__bf16)((e0 * av4.z + e1 * kr[i][2] + e2 * kr[i + 1][2] + e3 * kr[i + 2][2]) * inv);
        o[3] = (__bf16)((e0 * av4.w + e1 * kr[i][3] + e2 * kr[i + 1][3] + e3 * kr[i + 2][3]) * inv);
        *(bf16x4*)(att + (size_t)m * 1024 + c4) = o;
    }
}

extern "C" void kernel_launch(void* const* d_in, const int* in_sizes, int n_in,
                              void* d_out, int out_size, void* d_ws, size_t ws_size,
                              hipStream_t stream)
{
    const float* x    = (const float*)d_in[0];
    const float* ax   = (const float*)d_in[1];
    const float* WQ_w = (const float*)d_in[2];
    const float* WQ_b = (const float*)d_in[3];
    const float* WK_w = (const float*)d_in[4];
    const float* WK_b = (const float*)d_in[5];
    const float* WV_w = (const float*)d_in[6];
    const float* WV_b = (const float*)d_in[7];
    const float* WO_w = (const float*)d_in[8];
    const float* WO_b = (const float*)d_in[9];
    float* out = (float*)d_out;

    const int M = 8 * 4096;          // 32768 tokens

    // workspace layout
    char* ws = (char*)d_ws;
    __bf16* xb   = (__bf16*)(ws);                       //  67,108,864 B
    __bf16* Wqk  = (__bf16*)(ws + 67108864);            //   4,194,304 B  (2048 x 1024, N-major)
    __bf16* Wo   = (__bf16*)(ws + 71303168);            //   2,097,152 B  (1024 x 1024, N-major)
    __bf16* qk   = (__bf16*)(ws + 73400320);            // 134,217,728 B  (M x 2048)
    __bf16* att  = (__bf16*)(ws + 207618048);           //  67,108,864 B  (M x 1024)
    float*  akv  = (float*)(ws + 274726912);            //      65,536 B
    float*  akvp = (float*)(ws + 274792448);            //     524,288 B  (partials)

    // 1) x -> bf16
    {
        int n8 = (M * 1024) / 8;   // 4,194,304
        cvt_bf16_kernel<<<n8 / 256, 256, 0, stream>>>(x, xb, n8);
    }
    // 2) weight transpose+cast (one launch)
    transpose_cvt3_kernel<<<dim3(32, 32, 3), 256, 0, stream>>>(WQ_w, WK_w, WO_w, Wqk, Wo);
    // 3) global token projections (fp32), k-split + reduce
    akv_part_kernel<<<dim3(8, 2, 8), 256, 0, stream>>>(ax, WK_w, WV_w, akvp);
    akv_reduce_kernel<<<dim3(8, 2), 256, 0, stream>>>(akvp, WK_b, WV_b, akv);
    // 4) fused Q|K projection GEMM: (M x 2048) = xb @ [WQ|WK]; 256^2 8-phase, NT=8
    gemm256_kernel<8, false><<<(M / 256) * 8, 512, 0, stream>>>(
        xb, Wqk, WQ_b, WK_b, 1024, (void*)qk, M, 2048, 1024);
    // 5) attention -> att (bf16), 8 tokens/block
    attn_kernel<<<M / 8, 256, 0, stream>>>(qk, akv, att);
    // 6) output projection: out (M x 1024 fp32) = att @ WO + WO_b; NT=4
    gemm256_kernel<4, true><<<(M / 256) * 4, 512, 0, stream>>>(
        att, Wo, WO_b, WO_b, 1024, (void*)out, M, 1024, 1024);
}

// Round 3
// 545.206 us; speedup vs baseline: 1.0287x; 1.0032x over previous
//
#include <hip/hip_runtime.h>
#include <hip/hip_bf16.h>

typedef __bf16 bf16x8 __attribute__((ext_vector_type(8)));
typedef __bf16 bf16x4 __attribute__((ext_vector_type(4)));
typedef float  floatx4 __attribute__((ext_vector_type(4)));

#define L_SEQ 4096

// ---------------- fp32 -> bf16 cast, 8 elems/thread ----------------
__global__ void cvt_bf16_kernel(const float* __restrict__ src,
                                __bf16* __restrict__ dst, int n8)
{
    int i = blockIdx.x * blockDim.x + threadIdx.x;
    if (i >= n8) return;
    const float4* s = (const float4*)src + (size_t)i * 2;
    float4 f0 = s[0], f1 = s[1];
    bf16x8 o;
    o[0] = (__bf16)f0.x; o[1] = (__bf16)f0.y; o[2] = (__bf16)f0.z; o[3] = (__bf16)f0.w;
    o[4] = (__bf16)f1.x; o[5] = (__bf16)f1.y; o[6] = (__bf16)f1.z; o[7] = (__bf16)f1.w;
    *((bf16x8*)dst + i) = o;
}

// ---------------- 3 weight transposes in one launch: dst[n][k] = (bf16)src[k][n] ----------------
__global__ void transpose_cvt3_kernel(const float* __restrict__ WQ,
                                      const float* __restrict__ WK,
                                      const float* __restrict__ WO,
                                      __bf16* __restrict__ Wqk,
                                      __bf16* __restrict__ Wo)
{
    const int z = blockIdx.z;
    const float* src = (z == 0) ? WQ : (z == 1) ? WK : WO;
    __bf16* dst = (z == 0) ? Wqk : (z == 1) ? (Wqk + (size_t)1024 * 1024) : Wo;

    __shared__ float tile[32][33];
    int tx = threadIdx.x & 31, ty = threadIdx.x >> 5;   // 32 x 8
    int n0 = blockIdx.x * 32, k0 = blockIdx.y * 32;
    #pragma unroll
    for (int i = 0; i < 32; i += 8)
        tile[ty + i][tx] = src[(size_t)(k0 + ty + i) * 1024 + n0 + tx];
    __syncthreads();
    #pragma unroll
    for (int i = 0; i < 32; i += 8)
        dst[(size_t)(n0 + ty + i) * 1024 + k0 + tx] = (__bf16)tile[tx][ty + i];
}

// ---------------- global-token projections, k-split x8 ----------------
__global__ void akv_part_kernel(const float* __restrict__ ax,
                                const float* __restrict__ Wk,
                                const float* __restrict__ Wv,
                                float* __restrict__ part)
{
    int b = blockIdx.x, kv = blockIdx.y, z = blockIdx.z;
    int n = threadIdx.x * 4;
    const float* W   = kv ? Wv : Wk;
    const float* axr = ax + (size_t)b * 1024 + z * 128;
    float4 acc = {0.f, 0.f, 0.f, 0.f};
    for (int k = 0; k < 128; ++k) {
        float a = axr[k];
        float4 w = *(const float4*)(W + (size_t)(z * 128 + k) * 1024 + n);
        acc.x = fmaf(a, w.x, acc.x);
        acc.y = fmaf(a, w.y, acc.y);
        acc.z = fmaf(a, w.z, acc.z);
        acc.w = fmaf(a, w.w, acc.w);
    }
    *(float4*)(part + (((size_t)(b * 2 + kv)) * 8 + z) * 1024 + n) = acc;
}

__global__ void akv_reduce_kernel(const float* __restrict__ part,
                                  const float* __restrict__ bk,
                                  const float* __restrict__ bv,
                                  float* __restrict__ akv)
{
    int b = blockIdx.x, kv = blockIdx.y;
    int n = threadIdx.x * 4;
    float4 acc = *(const float4*)((kv ? bv : bk) + n);
    #pragma unroll
    for (int z = 0; z < 8; ++z) {
        float4 p = *(const float4*)(part + (((size_t)(b * 2 + kv)) * 8 + z) * 1024 + n);
        acc.x += p.x; acc.y += p.y; acc.z += p.z; acc.w += p.w;
    }
    *(float4*)(akv + ((size_t)b * 2 + kv) * 1024 + n) = acc;
}

// =====================================================================================
// 256x256 8-phase bf16 GEMM (T2+T3+T4+T5), C[M][N] = A[M][K] * Bt[N][K]^T + bias
//   R3 change (ONLY): waitcnt asm has NO "memory" clobber; ordering pinned with
//   __builtin_amdgcn_sched_barrier(0) after each wait (rule 18 / m201 recipe).
//   "memory"-clobbered asm acts as an optimizer fence and induces compiler-inserted
//   vmcnt(0) drains -> the counted-vmcnt pipeline (T4) degenerates to drain-mode
//   (m218 V1), which matches R2's 2x per-tile deficit (6.6k vs m201's 3.3k cy).
// =====================================================================================
#define GLDS(gp, lp) __builtin_amdgcn_global_load_lds(                              \
    (const __attribute__((address_space(1))) void*)(gp),                            \
    (__attribute__((address_space(3))) void*)(lp), 16, 0, 0)

#define STAGE_A(hi, kt, buf) do {                                                   \
    GLDS(A + aS[0][hi] + (size_t)(kt) * 64, smem + (buf) * 65536 + aD[0][hi]);      \
    GLDS(A + aS[1][hi] + (size_t)(kt) * 64, smem + (buf) * 65536 + aD[1][hi]);      \
} while (0)
#define STAGE_B(hi, kt, buf) do {                                                   \
    GLDS(Bt + bS[0][hi] + (size_t)(kt) * 64, smem + (buf) * 65536 + bD[0][hi]);     \
    GLDS(Bt + bS[1][hi] + (size_t)(kt) * 64, smem + (buf) * 65536 + bD[1][hi]);     \
} while (0)

#define RDA(cb, mi, kk) (*(const bf16x8*)(smem + (cb) + awoff + ((mi) << 11) + ((kk) << 10)))
#define RDB(cb, ni, kk) (*(const bf16x8*)(smem + (cb) + bwoff + ((ni) << 11) + ((kk) << 10)))
#define MFMA16(af, bfv, c) (c) = __builtin_amdgcn_mfma_f32_16x16x32_bf16((af), (bfv), (c), 0, 0, 0)

#define WAIT_LGKM0() do { asm volatile("s_waitcnt lgkmcnt(0)");                     \
    __builtin_amdgcn_sched_barrier(0); } while (0)
#define WAIT_VM(n) do { asm volatile("s_waitcnt vmcnt(" #n ")");                    \
    __builtin_amdgcn_sched_barrier(0); } while (0)

template <int NT, bool OUT_F32>
__global__ __launch_bounds__(512, 2) void gemm256_kernel(
    const __bf16* __restrict__ A, const __bf16* __restrict__ Bt,
    const float* __restrict__ b0, const float* __restrict__ b1, int nsplit,
    void* __restrict__ Cp, int M, int N, int K)
{
    __shared__ __align__(16) char smem[131072];   // [buf:2][A|B][32 subtiles][1024B]

    const int bid = blockIdx.x;
    const int xcd = bid & 7, g = bid >> 3;
    const int s = g & 31, r = g >> 5;             // s: co-resident slot, r: round
    int mt, nt;
    if constexpr (NT == 8) {
        nt = ((xcd & 1) << 2) | (s & 3);
        mt = (r << 5) + ((xcd >> 1) << 3) + (s >> 2);
    } else {
        nt = s & 3;
        mt = (xcd << 4) + (r << 3) + (s >> 2);
    }
    const int m0 = mt << 8, n0 = nt << 8;

    const int tid  = threadIdx.x;
    const int wave = tid >> 6, lane = tid & 63;
    const int l15  = lane & 15, quad = lane >> 4;
    const int ntile = K >> 6;

    // ---- staging addresses ----
    const int rowin = lane >> 2;                                   // row within subtile
    const int colel = ((lane & 3) << 3) ^ (((lane >> 5) & 1) << 4); // inverse-swizzled col (elems)
    size_t aS[2][2], bS[2][2];
    int    aD[2][2], bD[2][2];
    #pragma unroll
    for (int hi = 0; hi < 2; ++hi) {
        const int rgA = (wave & 3) + ((wave >> 2) << 3) + hi * 4;
        const int rgB = ((wave >> 1) << 2) + (wave & 1) + hi * 2;
        #pragma unroll
        for (int c = 0; c < 2; ++c) {
            aS[c][hi] = (size_t)(m0 + rgA * 16 + rowin) * K + c * 32 + colel;
            aD[c][hi] = (rgA * 2 + c) << 10;
            bS[c][hi] = (size_t)(n0 + rgB * 16 + rowin) * K + c * 32 + colel;
            bD[c][hi] = 32768 + ((rgB * 2 + c) << 10);
        }
    }

    // ---- fragment ds_read offsets (swizzled) ----
    const int alane = (l15 << 6) + ((quad << 4) ^ (((l15 >> 3) & 1) << 5));
    const int awoff = (((wave >> 2) * 8) << 11) + alane;            // + mi<<11 + kk<<10
    const int bwoff = 32768 + (((wave & 3) * 4) << 11) + alane;     // + ni<<11 + kk<<10

    floatx4 acc[8][4] = {};

    // ---- prologue: tile0 (4 halves) + tile1 h0..h2 (3 halves); keep 3 in flight ----
    STAGE_A(0, 0, 0); STAGE_A(1, 0, 0); STAGE_B(0, 0, 0); STAGE_B(1, 0, 0);
    STAGE_A(0, 1, 1); STAGE_B(0, 1, 1); STAGE_B(1, 1, 1);
    WAIT_VM(6);                                       // tile0's 8 loads retired
    __builtin_amdgcn_s_barrier();

    for (int t = 0; t < ntile; ++t) {
        const int p  = t & 1;
        const int cb = p * 65536;
        bf16x8 a0[4][2], a1[4][2], b0f[2][2], b1f[2][2];

        // ---------- phase 1 ----------
        #pragma unroll
        for (int mi = 0; mi < 4; ++mi) { a0[mi][0] = RDA(cb, mi, 0); a0[mi][1] = RDA(cb, mi, 1); }
        #pragma unroll
        for (int ni = 0; ni < 2; ++ni) { b0f[ni][0] = RDB(cb, ni, 0); b0f[ni][1] = RDB(cb, ni, 1); }
        if (t + 1 < ntile) STAGE_A(1, t + 1, p ^ 1);
        __builtin_amdgcn_s_barrier();
        WAIT_LGKM0();
        __builtin_amdgcn_s_setprio(1);
        #pragma unroll
        for (int mi = 0; mi < 4; ++mi)
            #pragma unroll
            for (int ni = 0; ni < 2; ++ni) {
                MFMA16(a0[mi][0], b0f[ni][0], acc[mi][ni]);
                MFMA16(a0[mi][1], b0f[ni][1], acc[mi][ni]);
            }
        __builtin_amdgcn_s_setprio(0);
        __builtin_amdgcn_s_barrier();

        // ---------- phase 2 ----------
        #pragma unroll
        for (int ni = 0; ni < 2; ++ni) { b1f[ni][0] = RDB(cb, ni + 2, 0); b1f[ni][1] = RDB(cb, ni + 2, 1); }
        if (t + 2 < ntile) STAGE_A(0, t + 2, p);
        __builtin_amdgcn_s_barrier();
        WAIT_LGKM0();
        __builtin_amdgcn_s_setprio(1);
        #pragma unroll
        for (int mi = 0; mi < 4; ++mi)
            #pragma unroll
            for (int ni = 0; ni < 2; ++ni) {
                MFMA16(a0[mi][0], b1f[ni][0], acc[mi][ni + 2]);
                MFMA16(a0[mi][1], b1f[ni][1], acc[mi][ni + 2]);
            }
        __builtin_amdgcn_s_setprio(0);
        __builtin_amdgcn_s_barrier();

        // ---------- phase 3 ----------
        #pragma unroll
        for (int mi = 0; mi < 4; ++mi) { a1[mi][0] = RDA(cb, mi + 4, 0); a1[mi][1] = RDA(cb, mi + 4, 1); }
        if (t + 2 < ntile) STAGE_B(0, t + 2, p);
        __builtin_amdgcn_s_barrier();
        WAIT_LGKM0();
        __builtin_amdgcn_s_setprio(1);
        #pragma unroll
        for (int mi = 0; mi < 4; ++mi)
            #pragma unroll
            for (int ni = 0; ni < 2; ++ni) {
                MFMA16(a1[mi][0], b1f[ni][0], acc[mi + 4][ni + 2]);
                MFMA16(a1[mi][1], b1f[ni][1], acc[mi + 4][ni + 2]);
            }
        __builtin_amdgcn_s_setprio(0);
        __builtin_amdgcn_s_barrier();

        // ---------- phase 4 (regs only; counted vmcnt once per K-tile) ----------
        if (t + 2 < ntile) {
            STAGE_B(1, t + 2, p);
            WAIT_VM(6);                               // (t+1) fully staged
        } else {
            WAIT_VM(0);                               // epilogue drain
        }
        __builtin_amdgcn_s_barrier();
        __builtin_amdgcn_s_setprio(1);
        #pragma unroll
        for (int mi = 0; mi < 4; ++mi)
            #pragma unroll
            for (int ni = 0; ni < 2; ++ni) {
                MFMA16(a1[mi][0], b0f[ni][0], acc[mi + 4][ni]);
                MFMA16(a1[mi][1], b0f[ni][1], acc[mi + 4][ni]);
            }
        __builtin_amdgcn_s_setprio(0);
        __builtin_amdgcn_s_barrier();
    }

    // ---- epilogue: C/D layout col = lane&15, row = quad*4 + r (m89/m91-verified) ----
    const int gmw = m0 + (wave >> 2) * 128;
    const int gnw = n0 + (wave & 3) * 64;
    #pragma unroll
    for (int ni = 0; ni < 4; ++ni) {
        int gn = gnw + ni * 16 + l15;
        float bv = (gn < nsplit) ? b0[gn] : b1[gn - nsplit];
        #pragma unroll
        for (int mi = 0; mi < 8; ++mi) {
            int gm = gmw + mi * 16 + quad * 4;
            #pragma unroll
            for (int r = 0; r < 4; ++r) {
                float v = acc[mi][ni][r] + bv;
                if constexpr (OUT_F32)
                    ((float*)Cp)[(size_t)(gm + r) * N + gn] = v;
                else
                    ((__bf16*)Cp)[(size_t)(gm + r) * N + gn] = (__bf16)v;
            }
        }
    }
}

// ---------------- attention: 8 tokens per block ----------------
__global__ void attn_kernel(const __bf16* __restrict__ qk,
                            const float* __restrict__ akv,
                            __bf16* __restrict__ att)
{
    const int t  = threadIdx.x;        // head = t>>4, 4 dims each
    const int c4 = t * 4;
    const int m0 = blockIdx.x * 8;     // 8 consecutive tokens, same batch (8 | 4096)
    const int l0 = m0 & (L_SEQ - 1);
    const int b  = m0 >> 12;

    float kr[10][4];
    #pragma unroll
    for (int j = 0; j < 10; ++j) {
        int ll = l0 - 1 + j;
        if (ll >= 0 && ll < L_SEQ) {
            bf16x4 kv = *(const bf16x4*)(qk + (size_t)(m0 - 1 + j) * 2048 + 1024 + c4);
            kr[j][0] = kv[0]; kr[j][1] = kv[1]; kr[j][2] = kv[2]; kr[j][3] = kv[3];
        } else {
            kr[j][0] = kr[j][1] = kr[j][2] = kr[j][3] = 0.f;
        }
    }
    float4 ak4 = *(const float4*)(akv + ((size_t)b * 2 + 0) * 1024 + c4);
    float4 av4 = *(const float4*)(akv + ((size_t)b * 2 + 1) * 1024 + c4);

    #pragma unroll
    for (int i = 0; i < 8; ++i) {
        const int m = m0 + i;
        bf16x4 qv = *(const bf16x4*)(qk + (size_t)m * 2048 + c4);
        float q0 = qv[0], q1 = qv[1], q2 = qv[2], q3 = qv[3];

        float p0 = q0 * ak4.x + q1 * ak4.y + q2 * ak4.z + q3 * ak4.w;
        float p1 = q0 * kr[i][0]     + q1 * kr[i][1]     + q2 * kr[i][2]     + q3 * kr[i][3];
        float p2 = q0 * kr[i + 1][0] + q1 * kr[i + 1][1] + q2 * kr[i + 1][2] + q3 * kr[i + 1][3];
        float p3 = q0 * kr[i + 2][0] + q1 * kr[i + 2][1] + q2 * kr[i + 2][2] + q3 * kr[i + 2][3];
        #pragma unroll
        for (int off = 1; off < 16; off <<= 1) {
            p0 += __shfl_xor(p0, off, 64);
            p1 += __shfl_xor(p1, off, 64);
            p2 += __shfl_xor(p2, off, 64);
            p3 += __shfl_xor(p3, off, 64);
        }
        const float sc = 0.125f;   // 1/sqrt(64)
        float s0 = p0 * sc, s1 = p1 * sc, s2 = p2 * sc, s3 = p3 * sc;
        float mx = fmaxf(fmaxf(s0, s1), fmaxf(s2, s3));
        float e0 = __expf(s0 - mx), e1 = __expf(s1 - mx), e2 = __expf(s2 - mx), e3 = __expf(s3 - mx);
        float inv = 1.f / (e0 + e1 + e2 + e3);

        bf16x4 o;
        o[0] = (__bf16)((e0 * av4.x + e1 * kr[i][0] + e2 * kr[i + 1][0] + e3 * kr[i + 2][0]) * inv);
        o[1] = (__bf16)((e0 * av4.y + e1 * kr[i][1] + e2 * kr[i + 1][1] + e3 * kr[i + 2][1]) * inv);
        o[2] = (__bf16)((e0 * av4.z + e1 * kr[i][2] + e2 * kr[i + 1][2] + e3 * kr[i + 2][2]) * inv);
        o[3] = (__bf16)((e0 * av4.w + e1 * kr[i][3] + e2 * kr[i + 1][3] + e3 * kr[i + 2][3]) * inv);
        *(bf16x4*)(att + (size_t)m * 1024 + c4) = o;
    }
}

extern "C" void kernel_launch(void* const* d_in, const int* in_sizes, int n_in,
                              void* d_out, int out_size, void* d_ws, size_t ws_size,
                              hipStream_t stream)
{
    const float* x    = (const float*)d_in[0];
    const float* ax   = (const float*)d_in[1];
    const float* WQ_w = (const float*)d_in[2];
    const float* WQ_b = (const float*)d_in[3];
    const float* WK_w = (const float*)d_in[4];
    const float* WK_b = (const float*)d_in[5];
    const float* WV_w = (const float*)d_in[6];
    const float* WV_b = (const float*)d_in[7];
    const float* WO_w = (const float*)d_in[8];
    const float* WO_b = (const float*)d_in[9];
    float* out = (float*)d_out;

    const int M = 8 * 4096;          // 32768 tokens

    // workspace layout
    char* ws = (char*)d_ws;
    __bf16* xb   = (__bf16*)(ws);                       //  67,108,864 B
    __bf16* Wqk  = (__bf16*)(ws + 67108864);            //   4,194,304 B  (2048 x 1024, N-major)
    __bf16* Wo   = (__bf16*)(ws + 71303168);            //   2,097,152 B  (1024 x 1024, N-major)
    __bf16* qk   = (__bf16*)(ws + 73400320);            // 134,217,728 B  (M x 2048)
    __bf16* att  = (__bf16*)(ws + 207618048);           //  67,108,864 B  (M x 1024)
    float*  akv  = (float*)(ws + 274726912);            //      65,536 B
    float*  akvp = (float*)(ws + 274792448);            //     524,288 B  (partials)

    // 1) x -> bf16
    {
        int n8 = (M * 1024) / 8;   // 4,194,304
        cvt_bf16_kernel<<<n8 / 256, 256, 0, stream>>>(x, xb, n8);
    }
    // 2) weight transpose+cast (one launch)
    transpose_cvt3_kernel<<<dim3(32, 32, 3), 256, 0, stream>>>(WQ_w, WK_w, WO_w, Wqk, Wo);
    // 3) global token projections (fp32), k-split + reduce
    akv_part_kernel<<<dim3(8, 2, 8), 256, 0, stream>>>(ax, WK_w, WV_w, akvp);
    akv_reduce_kernel<<<dim3(8, 2), 256, 0, stream>>>(akvp, WK_b, WV_b, akv);
    // 4) fused Q|K projection GEMM: (M x 2048) = xb @ [WQ|WK]; 256^2 8-phase, NT=8
    gemm256_kernel<8, false><<<(M / 256) * 8, 512, 0, stream>>>(
        xb, Wqk, WQ_b, WK_b, 1024, (void*)qk, M, 2048, 1024);
    // 5) attention -> att (bf16), 8 tokens/block
    attn_kernel<<<M / 8, 256, 0, stream>>>(qk, akv, att);
    // 6) output projection: out (M x 1024 fp32) = att @ WO + WO_b; NT=4
    gemm256_kernel<4, true><<<(M / 256) * 4, 512, 0, stream>>>(
        att, Wo, WO_b, WO_b, 1024, (void*)out, M, 1024, 1024);
}

// Round 4
// 544.441 us; speedup vs baseline: 1.0302x; 1.0014x over previous
//
#include <hip/hip_runtime.h>
#include <hip/hip_bf16.h>

typedef __bf16 bf16x8 __attribute__((ext_vector_type(8)));
typedef __bf16 bf16x4 __attribute__((ext_vector_type(4)));
typedef float  floatx4 __attribute__((ext_vector_type(4)));

#define L_SEQ 4096

// ---------------- fp32 -> bf16 cast, 8 elems/thread ----------------
__global__ void cvt_bf16_kernel(const float* __restrict__ src,
                                __bf16* __restrict__ dst, int n8)
{
    int i = blockIdx.x * blockDim.x + threadIdx.x;
    if (i >= n8) return;
    const float4* s = (const float4*)src + (size_t)i * 2;
    float4 f0 = s[0], f1 = s[1];
    bf16x8 o;
    o[0] = (__bf16)f0.x; o[1] = (__bf16)f0.y; o[2] = (__bf16)f0.z; o[3] = (__bf16)f0.w;
    o[4] = (__bf16)f1.x; o[5] = (__bf16)f1.y; o[6] = (__bf16)f1.z; o[7] = (__bf16)f1.w;
    *((bf16x8*)dst + i) = o;
}

// ---------------- 3 weight transposes in one launch: dst[n][k] = (bf16)src[k][n] ----------------
__global__ void transpose_cvt3_kernel(const float* __restrict__ WQ,
                                      const float* __restrict__ WK,
                                      const float* __restrict__ WO,
                                      __bf16* __restrict__ Wqk,
                                      __bf16* __restrict__ Wo)
{
    const int z = blockIdx.z;
    const float* src = (z == 0) ? WQ : (z == 1) ? WK : WO;
    __bf16* dst = (z == 0) ? Wqk : (z == 1) ? (Wqk + (size_t)1024 * 1024) : Wo;

    __shared__ float tile[32][33];
    int tx = threadIdx.x & 31, ty = threadIdx.x >> 5;   // 32 x 8
    int n0 = blockIdx.x * 32, k0 = blockIdx.y * 32;
    #pragma unroll
    for (int i = 0; i < 32; i += 8)
        tile[ty + i][tx] = src[(size_t)(k0 + ty + i) * 1024 + n0 + tx];
    __syncthreads();
    #pragma unroll
    for (int i = 0; i < 32; i += 8)
        dst[(size_t)(n0 + ty + i) * 1024 + k0 + tx] = (__bf16)tile[tx][ty + i];
}

// ---------------- global-token projections, k-split x8 ----------------
__global__ void akv_part_kernel(const float* __restrict__ ax,
                                const float* __restrict__ Wk,
                                const float* __restrict__ Wv,
                                float* __restrict__ part)
{
    int b = blockIdx.x, kv = blockIdx.y, z = blockIdx.z;
    int n = threadIdx.x * 4;
    const float* W   = kv ? Wv : Wk;
    const float* axr = ax + (size_t)b * 1024 + z * 128;
    float4 acc = {0.f, 0.f, 0.f, 0.f};
    for (int k = 0; k < 128; ++k) {
        float a = axr[k];
        float4 w = *(const float4*)(W + (size_t)(z * 128 + k) * 1024 + n);
        acc.x = fmaf(a, w.x, acc.x);
        acc.y = fmaf(a, w.y, acc.y);
        acc.z = fmaf(a, w.z, acc.z);
        acc.w = fmaf(a, w.w, acc.w);
    }
    *(float4*)(part + (((size_t)(b * 2 + kv)) * 8 + z) * 1024 + n) = acc;
}

__global__ void akv_reduce_kernel(const float* __restrict__ part,
                                  const float* __restrict__ bk,
                                  const float* __restrict__ bv,
                                  float* __restrict__ akv)
{
    int b = blockIdx.x, kv = blockIdx.y;
    int n = threadIdx.x * 4;
    float4 acc = *(const float4*)((kv ? bv : bk) + n);
    #pragma unroll
    for (int z = 0; z < 8; ++z) {
        float4 p = *(const float4*)(part + (((size_t)(b * 2 + kv)) * 8 + z) * 1024 + n);
        acc.x += p.x; acc.y += p.y; acc.z += p.z; acc.w += p.w;
    }
    *(float4*)(akv + ((size_t)b * 2 + kv) * 1024 + n) = acc;
}

// =====================================================================================
// 256x256 8-phase bf16 GEMM (T2+T3+T4+T5), C[M][N] = A[M][K] * Bt[N][K]^T + bias
//   R4 change (ONLY): raw inline-asm s_barrier instead of __builtin_amdgcn_s_barrier
//   inside the GEMM, fenced by sched_barrier(0). Hypothesis: the compiler's waitcnt
//   pass attaches a vmcnt(0) drain to the builtin barrier (conservative for
//   global_load_lds), degenerating the counted-vmcnt pipeline to drain-mode (m218 V1).
//   Raw asm is opaque to that pass. Cross-wave RAW (stage->read) is guaranteed by the
//   per-wave vmcnt(6) + barrier induction; WAR (read->overwrite) by lgkmcnt(0)-before-
//   MFMA + an intervening barrier. Audited for prologue, steady state, and epilogue.
// =====================================================================================
#define GLDS(gp, lp) __builtin_amdgcn_global_load_lds(                              \
    (const __attribute__((address_space(1))) void*)(gp),                            \
    (__attribute__((address_space(3))) void*)(lp), 16, 0, 0)

#define STAGE_A(hi, kt, buf) do {                                                   \
    GLDS(A + aS[0][hi] + (size_t)(kt) * 64, smem + (buf) * 65536 + aD[0][hi]);      \
    GLDS(A + aS[1][hi] + (size_t)(kt) * 64, smem + (buf) * 65536 + aD[1][hi]);      \
} while (0)
#define STAGE_B(hi, kt, buf) do {                                                   \
    GLDS(Bt + bS[0][hi] + (size_t)(kt) * 64, smem + (buf) * 65536 + bD[0][hi]);     \
    GLDS(Bt + bS[1][hi] + (size_t)(kt) * 64, smem + (buf) * 65536 + bD[1][hi]);     \
} while (0)

#define RDA(cb, mi, kk) (*(const bf16x8*)(smem + (cb) + awoff + ((mi) << 11) + ((kk) << 10)))
#define RDB(cb, ni, kk) (*(const bf16x8*)(smem + (cb) + bwoff + ((ni) << 11) + ((kk) << 10)))
#define MFMA16(af, bfv, c) (c) = __builtin_amdgcn_mfma_f32_16x16x32_bf16((af), (bfv), (c), 0, 0, 0)

#define WAIT_LGKM0() do { asm volatile("s_waitcnt lgkmcnt(0)");                     \
    __builtin_amdgcn_sched_barrier(0); } while (0)
#define WAIT_VM(n) do { asm volatile("s_waitcnt vmcnt(" #n ")");                    \
    __builtin_amdgcn_sched_barrier(0); } while (0)
// raw barrier: opaque to the waitcnt-insertion pass (no implicit vmcnt(0) drain);
// "memory" + sched_barrier(0) pin IR- and MIR-level ordering of LDS/VMEM ops around it
#define SBAR() do { __builtin_amdgcn_sched_barrier(0);                              \
    asm volatile("s_barrier" ::: "memory");                                         \
    __builtin_amdgcn_sched_barrier(0); } while (0)

template <int NT, bool OUT_F32>
__global__ __launch_bounds__(512, 2) void gemm256_kernel(
    const __bf16* __restrict__ A, const __bf16* __restrict__ Bt,
    const float* __restrict__ b0, const float* __restrict__ b1, int nsplit,
    void* __restrict__ Cp, int M, int N, int K)
{
    __shared__ __align__(16) char smem[131072];   // [buf:2][A|B][32 subtiles][1024B]

    const int bid = blockIdx.x;
    const int xcd = bid & 7, g = bid >> 3;
    const int s = g & 31, r = g >> 5;             // s: co-resident slot, r: round
    int mt, nt;
    if constexpr (NT == 8) {
        nt = ((xcd & 1) << 2) | (s & 3);
        mt = (r << 5) + ((xcd >> 1) << 3) + (s >> 2);
    } else {
        nt = s & 3;
        mt = (xcd << 4) + (r << 3) + (s >> 2);
    }
    const int m0 = mt << 8, n0 = nt << 8;

    const int tid  = threadIdx.x;
    const int wave = tid >> 6, lane = tid & 63;
    const int l15  = lane & 15, quad = lane >> 4;
    const int ntile = K >> 6;

    // ---- staging addresses ----
    const int rowin = lane >> 2;                                   // row within subtile
    const int colel = ((lane & 3) << 3) ^ (((lane >> 5) & 1) << 4); // inverse-swizzled col (elems)
    size_t aS[2][2], bS[2][2];
    int    aD[2][2], bD[2][2];
    #pragma unroll
    for (int hi = 0; hi < 2; ++hi) {
        const int rgA = (wave & 3) + ((wave >> 2) << 3) + hi * 4;
        const int rgB = ((wave >> 1) << 2) + (wave & 1) + hi * 2;
        #pragma unroll
        for (int c = 0; c < 2; ++c) {
            aS[c][hi] = (size_t)(m0 + rgA * 16 + rowin) * K + c * 32 + colel;
            aD[c][hi] = (rgA * 2 + c) << 10;
            bS[c][hi] = (size_t)(n0 + rgB * 16 + rowin) * K + c * 32 + colel;
            bD[c][hi] = 32768 + ((rgB * 2 + c) << 10);
        }
    }

    // ---- fragment ds_read offsets (swizzled) ----
    const int alane = (l15 << 6) + ((quad << 4) ^ (((l15 >> 3) & 1) << 5));
    const int awoff = (((wave >> 2) * 8) << 11) + alane;            // + mi<<11 + kk<<10
    const int bwoff = 32768 + (((wave & 3) * 4) << 11) + alane;     // + ni<<11 + kk<<10

    floatx4 acc[8][4] = {};

    // ---- prologue: tile0 (4 halves) + tile1 h0..h2 (3 halves); keep 3 in flight ----
    STAGE_A(0, 0, 0); STAGE_A(1, 0, 0); STAGE_B(0, 0, 0); STAGE_B(1, 0, 0);
    STAGE_A(0, 1, 1); STAGE_B(0, 1, 1); STAGE_B(1, 1, 1);
    WAIT_VM(6);                                       // tile0's 8 loads retired
    SBAR();

    for (int t = 0; t < ntile; ++t) {
        const int p  = t & 1;
        const int cb = p * 65536;
        bf16x8 a0[4][2], a1[4][2], b0f[2][2], b1f[2][2];

        // ---------- phase 1 ----------
        #pragma unroll
        for (int mi = 0; mi < 4; ++mi) { a0[mi][0] = RDA(cb, mi, 0); a0[mi][1] = RDA(cb, mi, 1); }
        #pragma unroll
        for (int ni = 0; ni < 2; ++ni) { b0f[ni][0] = RDB(cb, ni, 0); b0f[ni][1] = RDB(cb, ni, 1); }
        if (t + 1 < ntile) STAGE_A(1, t + 1, p ^ 1);
        SBAR();
        WAIT_LGKM0();
        __builtin_amdgcn_s_setprio(1);
        #pragma unroll
        for (int mi = 0; mi < 4; ++mi)
            #pragma unroll
            for (int ni = 0; ni < 2; ++ni) {
                MFMA16(a0[mi][0], b0f[ni][0], acc[mi][ni]);
                MFMA16(a0[mi][1], b0f[ni][1], acc[mi][ni]);
            }
        __builtin_amdgcn_s_setprio(0);
        SBAR();

        // ---------- phase 2 ----------
        #pragma unroll
        for (int ni = 0; ni < 2; ++ni) { b1f[ni][0] = RDB(cb, ni + 2, 0); b1f[ni][1] = RDB(cb, ni + 2, 1); }
        if (t + 2 < ntile) STAGE_A(0, t + 2, p);
        SBAR();
        WAIT_LGKM0();
        __builtin_amdgcn_s_setprio(1);
        #pragma unroll
        for (int mi = 0; mi < 4; ++mi)
            #pragma unroll
            for (int ni = 0; ni < 2; ++ni) {
                MFMA16(a0[mi][0], b1f[ni][0], acc[mi][ni + 2]);
                MFMA16(a0[mi][1], b1f[ni][1], acc[mi][ni + 2]);
            }
        __builtin_amdgcn_s_setprio(0);
        SBAR();

        // ---------- phase 3 ----------
        #pragma unroll
        for (int mi = 0; mi < 4; ++mi) { a1[mi][0] = RDA(cb, mi + 4, 0); a1[mi][1] = RDA(cb, mi + 4, 1); }
        if (t + 2 < ntile) STAGE_B(0, t + 2, p);
        SBAR();
        WAIT_LGKM0();
        __builtin_amdgcn_s_setprio(1);
        #pragma unroll
        for (int mi = 0; mi < 4; ++mi)
            #pragma unroll
            for (int ni = 0; ni < 2; ++ni) {
                MFMA16(a1[mi][0], b1f[ni][0], acc[mi + 4][ni + 2]);
                MFMA16(a1[mi][1], b1f[ni][1], acc[mi + 4][ni + 2]);
            }
        __builtin_amdgcn_s_setprio(0);
        SBAR();

        // ---------- phase 4 (regs only; counted vmcnt once per K-tile) ----------
        if (t + 2 < ntile) {
            STAGE_B(1, t + 2, p);
            WAIT_VM(6);                               // (t+1) fully staged
        } else {
            WAIT_VM(0);                               // epilogue drain
        }
        SBAR();
        __builtin_amdgcn_s_setprio(1);
        #pragma unroll
        for (int mi = 0; mi < 4; ++mi)
            #pragma unroll
            for (int ni = 0; ni < 2; ++ni) {
                MFMA16(a1[mi][0], b0f[ni][0], acc[mi + 4][ni]);
                MFMA16(a1[mi][1], b0f[ni][1], acc[mi + 4][ni]);
            }
        __builtin_amdgcn_s_setprio(0);
        SBAR();
    }

    // ---- epilogue: C/D layout col = lane&15, row = quad*4 + r (m89/m91-verified) ----
    const int gmw = m0 + (wave >> 2) * 128;
    const int gnw = n0 + (wave & 3) * 64;
    #pragma unroll
    for (int ni = 0; ni < 4; ++ni) {
        int gn = gnw + ni * 16 + l15;
        float bv = (gn < nsplit) ? b0[gn] : b1[gn - nsplit];
        #pragma unroll
        for (int mi = 0; mi < 8; ++mi) {
            int gm = gmw + mi * 16 + quad * 4;
            #pragma unroll
            for (int r = 0; r < 4; ++r) {
                float v = acc[mi][ni][r] + bv;
                if constexpr (OUT_F32)
                    ((float*)Cp)[(size_t)(gm + r) * N + gn] = v;
                else
                    ((__bf16*)Cp)[(size_t)(gm + r) * N + gn] = (__bf16)v;
            }
        }
    }
}

// ---------------- attention: 8 tokens per block ----------------
__global__ void attn_kernel(const __bf16* __restrict__ qk,
                            const float* __restrict__ akv,
                            __bf16* __restrict__ att)
{
    const int t  = threadIdx.x;        // head = t>>4, 4 dims each
    const int c4 = t * 4;
    const int m0 = blockIdx.x * 8;     // 8 consecutive tokens, same batch (8 | 4096)
    const int l0 = m0 & (L_SEQ - 1);
    const int b  = m0 >> 12;

    float kr[10][4];
    #pragma unroll
    for (int j = 0; j < 10; ++j) {
        int ll = l0 - 1 + j;
        if (ll >= 0 && ll < L_SEQ) {
            bf16x4 kv = *(const bf16x4*)(qk + (size_t)(m0 - 1 + j) * 2048 + 1024 + c4);
            kr[j][0] = kv[0]; kr[j][1] = kv[1]; kr[j][2] = kv[2]; kr[j][3] = kv[3];
        } else {
            kr[j][0] = kr[j][1] = kr[j][2] = kr[j][3] = 0.f;
        }
    }
    float4 ak4 = *(const float4*)(akv + ((size_t)b * 2 + 0) * 1024 + c4);
    float4 av4 = *(const float4*)(akv + ((size_t)b * 2 + 1) * 1024 + c4);

    #pragma unroll
    for (int i = 0; i < 8; ++i) {
        const int m = m0 + i;
        bf16x4 qv = *(const bf16x4*)(qk + (size_t)m * 2048 + c4);
        float q0 = qv[0], q1 = qv[1], q2 = qv[2], q3 = qv[3];

        float p0 = q0 * ak4.x + q1 * ak4.y + q2 * ak4.z + q3 * ak4.w;
        float p1 = q0 * kr[i][0]     + q1 * kr[i][1]     + q2 * kr[i][2]     + q3 * kr[i][3];
        float p2 = q0 * kr[i + 1][0] + q1 * kr[i + 1][1] + q2 * kr[i + 1][2] + q3 * kr[i + 1][3];
        float p3 = q0 * kr[i + 2][0] + q1 * kr[i + 2][1] + q2 * kr[i + 2][2] + q3 * kr[i + 2][3];
        #pragma unroll
        for (int off = 1; off < 16; off <<= 1) {
            p0 += __shfl_xor(p0, off, 64);
            p1 += __shfl_xor(p1, off, 64);
            p2 += __shfl_xor(p2, off, 64);
            p3 += __shfl_xor(p3, off, 64);
        }
        const float sc = 0.125f;   // 1/sqrt(64)
        float s0 = p0 * sc, s1 = p1 * sc, s2 = p2 * sc, s3 = p3 * sc;
        float mx = fmaxf(fmaxf(s0, s1), fmaxf(s2, s3));
        float e0 = __expf(s0 - mx), e1 = __expf(s1 - mx), e2 = __expf(s2 - mx), e3 = __expf(s3 - mx);
        float inv = 1.f / (e0 + e1 + e2 + e3);

        bf16x4 o;
        o[0] = (__bf16)((e0 * av4.x + e1 * kr[i][0] + e2 * kr[i + 1][0] + e3 * kr[i + 2][0]) * inv);
        o[1] = (__bf16)((e0 * av4.y + e1 * kr[i][1] + e2 * kr[i + 1][1] + e3 * kr[i + 2][1]) * inv);
        o[2] = (__bf16)((e0 * av4.z + e1 * kr[i][2] + e2 * kr[i + 1][2] + e3 * kr[i + 2][2]) * inv);
        o[3] = (__bf16)((e0 * av4.w + e1 * kr[i][3] + e2 * kr[i + 1][3] + e3 * kr[i + 2][3]) * inv);
        *(bf16x4*)(att + (size_t)m * 1024 + c4) = o;
    }
}

extern "C" void kernel_launch(void* const* d_in, const int* in_sizes, int n_in,
                              void* d_out, int out_size, void* d_ws, size_t ws_size,
                              hipStream_t stream)
{
    const float* x    = (const float*)d_in[0];
    const float* ax   = (const float*)d_in[1];
    const float* WQ_w = (const float*)d_in[2];
    const float* WQ_b = (const float*)d_in[3];
    const float* WK_w = (const float*)d_in[4];
    const float* WK_b = (const float*)d_in[5];
    const float* WV_w = (const float*)d_in[6];
    const float* WV_b = (const float*)d_in[7];
    const float* WO_w = (const float*)d_in[8];
    const float* WO_b = (const float*)d_in[9];
    float* out = (float*)d_out;

    const int M = 8 * 4096;          // 32768 tokens

    // workspace layout
    char* ws = (char*)d_ws;
    __bf16* xb   = (__bf16*)(ws);                       //  67,108,864 B
    __bf16* Wqk  = (__bf16*)(ws + 67108864);            //   4,194,304 B  (2048 x 1024, N-major)
    __bf16* Wo   = (__bf16*)(ws + 71303168);            //   2,097,152 B  (1024 x 1024, N-major)
    __bf16* qk   = (__bf16*)(ws + 73400320);            // 134,217,728 B  (M x 2048)
    __bf16* att  = (__bf16*)(ws + 207618048);           //  67,108,864 B  (M x 1024)
    float*  akv  = (float*)(ws + 274726912);            //      65,536 B
    float*  akvp = (float*)(ws + 274792448);            //     524,288 B  (partials)

    // 1) x -> bf16
    {
        int n8 = (M * 1024) / 8;   // 4,194,304
        cvt_bf16_kernel<<<n8 / 256, 256, 0, stream>>>(x, xb, n8);
    }
    // 2) weight transpose+cast (one launch)
    transpose_cvt3_kernel<<<dim3(32, 32, 3), 256, 0, stream>>>(WQ_w, WK_w, WO_w, Wqk, Wo);
    // 3) global token projections (fp32), k-split + reduce
    akv_part_kernel<<<dim3(8, 2, 8), 256, 0, stream>>>(ax, WK_w, WV_w, akvp);
    akv_reduce_kernel<<<dim3(8, 2), 256, 0, stream>>>(akvp, WK_b, WV_b, akv);
    // 4) fused Q|K projection GEMM: (M x 2048) = xb @ [WQ|WK]; 256^2 8-phase, NT=8
    gemm256_kernel<8, false><<<(M / 256) * 8, 512, 0, stream>>>(
        xb, Wqk, WQ_b, WK_b, 1024, (void*)qk, M, 2048, 1024);
    // 5) attention -> att (bf16), 8 tokens/block
    attn_kernel<<<M / 8, 256, 0, stream>>>(qk, akv, att);
    // 6) output projection: out (M x 1024 fp32) = att @ WO + WO_b; NT=4
    gemm256_kernel<4, true><<<(M / 256) * 4, 512, 0, stream>>>(
        att, Wo, WO_b, WO_b, 1024, (void*)out, M, 1024, 1024);
}